// Round 15
// baseline (168.313 us; speedup 1.0000x reference)
//
#include <hip/hip_runtime.h>
#include <hip/hip_bf16.h>
#include <type_traits>
#include <math.h>

typedef __bf16 bf16x8 __attribute__((ext_vector_type(8)));
typedef float floatx4 __attribute__((ext_vector_type(4)));
typedef float floatx16 __attribute__((ext_vector_type(16)));

#define S_LEN 2048
#define D_DIM 128
#define NTOK (2 * 16 * 2048)  // B*H*S = 65536 rows
#define KVB 64
#define NKV (S_LEN / KVB)     // 32 kv tiles

// ---------------------------------------------------------------------------
// proj body: stages W once, then processes 4 chunks of 64 rows.
// ---------------------------------------------------------------------------
template <typename TIN, typename TOUT>
__device__ __forceinline__ void proj_body4(
    const TIN* __restrict__ x, const float* __restrict__ W,
    const float* __restrict__ b, TOUT* __restrict__ y, float out_scale,
    int chunk0, __bf16 (*Wl)[128]) {
  const int tid = threadIdx.x;
  const int wave = tid >> 6, lane = tid & 63;
  const int g = lane >> 4, lr = lane & 15;

  for (int it = 0; it < 16; ++it) {
    int lin = it * 1024 + tid * 4;
    float4 w4 = *reinterpret_cast<const float4*>(W + lin);
    int r = lin >> 7, c = lin & 127;
    Wl[r][c]     = (__bf16)w4.x;
    Wl[r][c + 1] = (__bf16)w4.y;
    Wl[r][c + 2] = (__bf16)w4.z;
    Wl[r][c + 3] = (__bf16)w4.w;
  }
  __syncthreads();

  float be[8];
#pragma unroll
  for (int nt = 0; nt < 8; ++nt) be[nt] = b[nt * 16 + lr];

  for (int ch = 0; ch < 4; ++ch) {
    const int rbase = (chunk0 + ch) * 64;
    const int arow = rbase + wave * 16 + lr;

    floatx4 acc[8];
#pragma unroll
    for (int i = 0; i < 8; ++i) acc[i] = floatx4{0.f, 0.f, 0.f, 0.f};

#pragma unroll
    for (int kc = 0; kc < 4; ++kc) {
      bf16x8 af;
      const TIN* xp = x + (size_t)arow * D_DIM + kc * 32 + g * 8;
      if constexpr (std::is_same<TIN, float>::value) {
        float4 f0 = *reinterpret_cast<const float4*>(xp);
        float4 f1 = *reinterpret_cast<const float4*>(xp + 4);
        af[0] = (__bf16)f0.x; af[1] = (__bf16)f0.y;
        af[2] = (__bf16)f0.z; af[3] = (__bf16)f0.w;
        af[4] = (__bf16)f1.x; af[5] = (__bf16)f1.y;
        af[6] = (__bf16)f1.z; af[7] = (__bf16)f1.w;
      } else {
        af = *reinterpret_cast<const bf16x8*>(xp);
      }
#pragma unroll
      for (int nt = 0; nt < 8; ++nt) {
        bf16x8 wf = *reinterpret_cast<const bf16x8*>(&Wl[nt * 16 + lr][kc * 32 + g * 8]);
        acc[nt] = __builtin_amdgcn_mfma_f32_16x16x32_bf16(af, wf, acc[nt], 0, 0, 0);
      }
    }

#pragma unroll
    for (int nt = 0; nt < 8; ++nt) {
      int e = nt * 16 + lr;
#pragma unroll
      for (int j = 0; j < 4; ++j) {
        int row = rbase + wave * 16 + g * 4 + j;
        float val = (acc[nt][j] + be[nt]) * out_scale;
        y[(size_t)row * D_DIM + e] = (TOUT)val;
      }
    }
  }
}

__global__ __launch_bounds__(256) void qkv_proj_kernel(
    const float* __restrict__ xq, const float* __restrict__ xk,
    const float* __restrict__ xv, const float* __restrict__ Wq,
    const float* __restrict__ Wk, const float* __restrict__ Wv,
    const float* __restrict__ bq, const float* __restrict__ bk,
    const float* __restrict__ bv, __bf16* yq, __bf16* yk, __bf16* yv,
    float qscale) {
  __shared__ alignas(16) __bf16 Wl[128][128];
  const int which = blockIdx.y;
  const float* x = which == 0 ? xq : which == 1 ? xk : xv;
  const float* W = which == 0 ? Wq : which == 1 ? Wk : Wv;
  const float* b = which == 0 ? bq : which == 1 ? bk : bv;
  __bf16* y = which == 0 ? yq : which == 1 ? yk : yv;
  float sc = which == 0 ? qscale : 1.0f;
  proj_body4<float, __bf16>(x, W, b, y, sc, blockIdx.x * 4, Wl);
}

__global__ __launch_bounds__(256) void o_proj_kernel(
    const __bf16* __restrict__ x, const float* __restrict__ W,
    const float* __restrict__ b, float* __restrict__ y) {
  __shared__ alignas(16) __bf16 Wl[128][128];
  proj_body4<__bf16, float>(x, W, b, y, 1.0f, blockIdx.x * 4, Wl);
}

// ---------------------------------------------------------------------------
// epilogue swizzle (O tile + Wo tile staging)
__device__ __forceinline__ unsigned swz(int row, unsigned byteoff) {
  return byteoff ^ (((unsigned)(row ^ (row >> 3)) & 7u) << 4);
}

__device__ __forceinline__ unsigned pack2(float lo, float hi) {
  union { __bf16 h[2]; unsigned u; } r;
  r.h[0] = (__bf16)lo; r.h[1] = (__bf16)hi;
  return r.u;
}

// ---------------------------------------------------------------------------
// attn_fused_kernel v15: K read DIRECTLY from global (L1/L2-resident) into
// per-wave kf[16] registers, prefetched one tile ahead (issued right after
// QK(t) consumes the regs -> ~2000 cyc latency cover). Removes all K LDS
// traffic (reads, writes, staging) — DS cycles per CU-tile roughly halve;
// K moves to the near-idle VMEM pipe. V stays LDS double-buffered (32 KB,
// buffers at 0/16384). Everything else = r13/r14: single barrier/tile,
// swapped 32x32x16 QK^T, in-register exp2 softmax, T13 defer-rescale,
// in-register P^T via permlane32_swap, fused O-projection epilogue (uses
// full 64 KB LDS after the k-loop).
// K fragment: lane ql needs K[kv=kvh*32+ql][kc*16+h*8 .. +7] (16 B) ->
// per-lane base kgp = kp + ql*128 + h*8, offsets kvh*4096 + kc*16 elems.
// ---------------------------------------------------------------------------
__global__ __launch_bounds__(256, 2) void attn_fused_kernel(
    const __bf16* __restrict__ q, const __bf16* __restrict__ k,
    const __bf16* __restrict__ v, const float* __restrict__ Wo,
    const float* __restrict__ bo, float* __restrict__ out) {
  __shared__ alignas(16) unsigned char smem[65536];

  const int tid = threadIdx.x;
  const int wave = tid >> 6, lane = tid & 63;
  const int ql = lane & 31;
  const int h = lane >> 5;

  const int bh = blockIdx.x;
  const int qbase = blockIdx.y * 128;
  const __bf16* qp = q + (size_t)bh * S_LEN * D_DIM;
  const __bf16* kp = k + (size_t)bh * S_LEN * D_DIM;
  const __bf16* vp = v + (size_t)bh * S_LEN * D_DIM;

  const int qrow = qbase + wave * 32 + ql;
  bf16x8 qf[8];
#pragma unroll
  for (int kc = 0; kc < 8; ++kc)
    qf[kc] = *reinterpret_cast<const bf16x8*>(
        qp + (size_t)qrow * D_DIM + kc * 16 + h * 8);

  floatx16 ot[4];
#pragma unroll
  for (int d = 0; d < 4; ++d)
#pragma unroll
    for (int r = 0; r < 16; ++r) ot[d][r] = 0.f;
  float m_r = -1e30f, l_r = 0.f;

  // V staging map: 4 consecutive kv rows per thread
  const int cc = tid & 15;
  const int pr4 = (tid >> 4) * 4;
  const int ce = cc * 8;

  // ---- lane-resident V LDS address bases (buffers at 0 / 16384) ----
  const unsigned Rv0 = (unsigned)(h * 2048) +
                       (((unsigned)(ql * 16)) ^ (((unsigned)(ql >> 3)) << 4));
  const unsigned Rv1 = Rv0 ^ 64u;
  const unsigned kx = ((unsigned)(cc & 7)) << 4;
  unsigned Wv_[8];
  {
    unsigned vbase = (unsigned)((pr4 >> 3) * 2048 + ce * 16 + (pr4 & 7) * 2);
#pragma unroll
    for (int e = 0; e < 8; ++e)
      Wv_[e] = vbase | (((unsigned)e << 4) ^ kx);
  }

  // ---- per-lane K global pointer + prologue kf prefetch (tile 0) ----
  const __bf16* kgp = kp + (size_t)(ql * 128 + h * 8);
  bf16x8 kf[16];  // [kvh*8+kc]
#pragma unroll
  for (int kvh = 0; kvh < 2; ++kvh)
#pragma unroll
    for (int kc = 0; kc < 8; ++kc)
      kf[kvh * 8 + kc] =
          *reinterpret_cast<const bf16x8*>(kgp + kvh * 4096 + kc * 16);
  kgp += (size_t)KVB * D_DIM;

  // ---- prologue: stage V tile 0 into buf 0 ----
  {
    const __bf16* vr = vp + (size_t)pr4 * D_DIM + ce;
    union { bf16x8 v8; unsigned short s[8]; } vR[4];
#pragma unroll
    for (int j = 0; j < 4; ++j)
      vR[j].v8 = *reinterpret_cast<const bf16x8*>(vr + j * D_DIM);
#pragma unroll
    for (int e = 0; e < 8; ++e) {
      uint2 w;
      w.x = (unsigned)vR[0].s[e] | ((unsigned)vR[1].s[e] << 16);
      w.y = (unsigned)vR[2].s[e] | ((unsigned)vR[3].s[e] << 16);
      *reinterpret_cast<uint2*>(smem + Wv_[e]) = w;
    }
  }

  const __bf16* vrp = vp + ((size_t)KVB + pr4) * D_DIM + ce;

#pragma unroll 2
  for (int t = 0; t < NKV; ++t) {
    const unsigned cb = (unsigned)(t & 1) * 16384u;
    const bool hn = (t + 1 < NKV);

    __syncthreads();  // V buf[cur] staged; all waves done with body t-1

    union { bf16x8 v8; unsigned short s[8]; } vR[4];
    if (hn) {  // issue V(t+1) global loads (consumed mid-body)
#pragma unroll
      for (int j = 0; j < 4; ++j)
        vR[j].v8 = *reinterpret_cast<const bf16x8*>(vrp + j * D_DIM);
      vrp += (size_t)KVB * D_DIM;
    }

    // ---- QK^T from kf registers ----
    floatx16 st[2];
#pragma unroll
    for (int kvh = 0; kvh < 2; ++kvh)
#pragma unroll
      for (int r = 0; r < 16; ++r) st[kvh][r] = 0.f;
    __builtin_amdgcn_s_setprio(1);
#pragma unroll
    for (int kc = 0; kc < 8; ++kc) {
      st[0] = __builtin_amdgcn_mfma_f32_32x32x16_bf16(kf[kc], qf[kc], st[0], 0, 0, 0);
      st[1] = __builtin_amdgcn_mfma_f32_32x32x16_bf16(kf[8 + kc], qf[kc], st[1], 0, 0, 0);
    }
    __builtin_amdgcn_s_setprio(0);

    // ---- prefetch kf for tile t+1 (regs just consumed; ~2000 cyc cover) --
    if (hn) {
#pragma unroll
      for (int kvh = 0; kvh < 2; ++kvh)
#pragma unroll
        for (int kc = 0; kc < 8; ++kc)
          kf[kvh * 8 + kc] =
              *reinterpret_cast<const bf16x8*>(kgp + kvh * 4096 + kc * 16);
      kgp += (size_t)KVB * D_DIM;
    }

    // ---- write V(t+1) into buf[nxt] (drains under softmax + PV) ----
    if (hn) {
      const unsigned nb = cb ^ 16384u;
#pragma unroll
      for (int e = 0; e < 8; ++e) {
        uint2 w;
        w.x = (unsigned)vR[0].s[e] | ((unsigned)vR[1].s[e] << 16);
        w.y = (unsigned)vR[2].s[e] | ((unsigned)vR[3].s[e] << 16);
        *reinterpret_cast<uint2*>(smem + nb + Wv_[e]) = w;
      }
    }

    // ---- softmax (exp2 domain), tree max/sum, T13 defer-rescale ----
    float t8[8];
#pragma unroll
    for (int i = 0; i < 8; ++i)
      t8[i] = fmaxf(fmaxf(st[0][i], st[0][i + 8]), fmaxf(st[1][i], st[1][i + 8]));
    float pmax = fmaxf(fmaxf(fmaxf(t8[0], t8[4]), fmaxf(t8[1], t8[5])),
                       fmaxf(fmaxf(t8[2], t8[6]), fmaxf(t8[3], t8[7])));
    pmax = fmaxf(pmax, __shfl_xor(pmax, 32));
    if (!__all(pmax - m_r <= 8.0f)) {
      float mnew = fmaxf(m_r, pmax);
      float sc_f = __builtin_amdgcn_exp2f(m_r - mnew);
      m_r = mnew;
      l_r *= sc_f;
#pragma unroll
      for (int d = 0; d < 4; ++d)
#pragma unroll
        for (int r = 0; r < 16; ++r) ot[d][r] *= sc_f;
    }
#pragma unroll
    for (int kvh = 0; kvh < 2; ++kvh)
#pragma unroll
      for (int r = 0; r < 16; ++r)
        st[kvh][r] = __builtin_amdgcn_exp2f(st[kvh][r] - m_r);
    float s8[8];
#pragma unroll
    for (int i = 0; i < 8; ++i)
      s8[i] = (st[0][i] + st[0][i + 8]) + (st[1][i] + st[1][i + 8]);
    float psum = ((s8[0] + s8[4]) + (s8[1] + s8[5])) +
                 ((s8[2] + s8[6]) + (s8[3] + s8[7]));
    psum += __shfl_xor(psum, 32);
    l_r += psum;

    // ---- P^T B-fragments + PV (V from LDS buf[cur]) ----
#pragma unroll
    for (int ks = 0; ks < 4; ++ks) {
      const int kvh = ks >> 1;
      const int r2a = (2 * ks) & 3;
      const int r2b = r2a + 1;
      unsigned ua0 = pack2(st[kvh][r2a * 4 + 0], st[kvh][r2a * 4 + 1]);
      unsigned ua1 = pack2(st[kvh][r2a * 4 + 2], st[kvh][r2a * 4 + 3]);
      unsigned ub0 = pack2(st[kvh][r2b * 4 + 0], st[kvh][r2b * 4 + 1]);
      unsigned ub1 = pack2(st[kvh][r2b * 4 + 2], st[kvh][r2b * 4 + 3]);
      union { unsigned u[4]; bf16x8 v8; } pw;
#if __has_builtin(__builtin_amdgcn_permlane32_swap)
      {
        auto r0 = __builtin_amdgcn_permlane32_swap(ua0, ub0, false, false);
        auto r1 = __builtin_amdgcn_permlane32_swap(ua1, ub1, false, false);
        pw.u[0] = r0[0];
        pw.u[1] = r1[0];
        pw.u[2] = r0[1];
        pw.u[3] = r1[1];
      }
#else
      {
        unsigned a0x = __shfl_xor(ua0, 32), a1x = __shfl_xor(ua1, 32);
        unsigned b0x = __shfl_xor(ub0, 32), b1x = __shfl_xor(ub1, 32);
        pw.u[0] = h ? b0x : ua0;
        pw.u[1] = h ? b1x : ua1;
        pw.u[2] = h ? ub0 : a0x;
        pw.u[3] = h ? ub1 : a1x;
      }
#endif
      __builtin_amdgcn_s_setprio(1);
#pragma unroll
      for (int db = 0; db < 4; ++db) {
        const unsigned base = (db & 1) ? Rv1 : Rv0;
        bf16x8 vf = *reinterpret_cast<const bf16x8*>(
            smem + cb + base + (unsigned)(ks * 4096 + db * 512));
        ot[db] = __builtin_amdgcn_mfma_f32_32x32x16_bf16(vf, pw.v8, ot[db], 0, 0, 0);
      }
      __builtin_amdgcn_s_setprio(0);
    }
  }

  // ==== fused epilogue: O -> LDS; Wo -> LDS; proj; write fp32 d_out ====
  __syncthreads();  // all waves done with V LDS

  // (a) O^T -> LDS[0..32K) as row-major bf16 (divided by l), swizzled
  {
    const float inv_l = 1.0f / l_r;
    const int qloc = wave * 32 + ql;
#pragma unroll
    for (int db = 0; db < 4; ++db)
#pragma unroll
      for (int r = 0; r < 16; ++r) {
        int d = db * 32 + (r & 3) + 8 * (r >> 2) + 4 * h;
        *reinterpret_cast<__bf16*>(smem + swz(qloc, qloc * 256u + d * 2u)) =
            (__bf16)(ot[db][r] * inv_l);
      }
  }
  // (b) Wo fp32 -> LDS[32K..64K) as bf16, swizzled rows
  for (int it = 0; it < 16; ++it) {
    int lin = it * 1024 + tid * 4;
    float4 w4 = *reinterpret_cast<const float4*>(Wo + lin);
    int r = lin >> 7, c = lin & 127;
    unsigned off = 32768u + swz(r, (unsigned)(r * 256 + c * 2));
    __bf16 b4[4] = {(__bf16)w4.x, (__bf16)w4.y, (__bf16)w4.z, (__bf16)w4.w};
    *reinterpret_cast<uint2*>(smem + off) = *reinterpret_cast<uint2*>(b4);
  }
  __syncthreads();

  // (c) proj: out[q][e] = O[q][:] . Wo[e][:] + bo[e]
  const int g4 = lane >> 4;      // 0..3 (k-slice group)
  const int lr = lane & 15;      // A row / C col
  float be[8];
#pragma unroll
  for (int nt = 0; nt < 8; ++nt) be[nt] = bo[nt * 16 + lr];

#pragma unroll
  for (int rt = 0; rt < 2; ++rt) {
    const int arow = wave * 32 + rt * 16 + lr;  // local O row
    floatx4 acc[8];
#pragma unroll
    for (int i = 0; i < 8; ++i) acc[i] = floatx4{0.f, 0.f, 0.f, 0.f};
#pragma unroll
    for (int kc = 0; kc < 4; ++kc) {
      bf16x8 af = *reinterpret_cast<const bf16x8*>(
          smem + swz(arow, (unsigned)(arow * 256 + (kc * 32 + g4 * 8) * 2)));
#pragma unroll
      for (int nt = 0; nt < 8; ++nt) {
        int wrow = nt * 16 + lr;
        bf16x8 wf = *reinterpret_cast<const bf16x8*>(
            smem + 32768u + swz(wrow, (unsigned)(wrow * 256 + (kc * 32 + g4 * 8) * 2)));
        acc[nt] = __builtin_amdgcn_mfma_f32_16x16x32_bf16(af, wf, acc[nt], 0, 0, 0);
      }
    }
#pragma unroll
    for (int nt = 0; nt < 8; ++nt) {
      int e = nt * 16 + lr;
#pragma unroll
      for (int j = 0; j < 4; ++j) {
        int row = qbase + wave * 32 + rt * 16 + g4 * 4 + j;
        out[((size_t)bh * S_LEN + row) * D_DIM + e] = acc[nt][j] + be[nt];
      }
    }
  }
}

// ---------------------------------------------------------------------------
// attn_kernel (fallback path, r13-proven; only used if ws_size too small)
// ---------------------------------------------------------------------------
__global__ __launch_bounds__(256, 2) void attn_kernel(
    const __bf16* __restrict__ q, const __bf16* __restrict__ k,
    const __bf16* __restrict__ v, __bf16* __restrict__ o) {
  __shared__ alignas(16) unsigned char smem[65536];

  const int tid = threadIdx.x;
  const int wave = tid >> 6, lane = tid & 63;
  const int ql = lane & 31;
  const int h = lane >> 5;

  const int bh = blockIdx.x;
  const int qbase = blockIdx.y * 128;
  const __bf16* qp = q + (size_t)bh * S_LEN * D_DIM;
  const __bf16* kp = k + (size_t)bh * S_LEN * D_DIM;
  const __bf16* vp = v + (size_t)bh * S_LEN * D_DIM;
  __bf16* op = o + (size_t)bh * S_LEN * D_DIM;

  const int qrow = qbase + wave * 32 + ql;
  bf16x8 qf[8];
#pragma unroll
  for (int kc = 0; kc < 8; ++kc)
    qf[kc] = *reinterpret_cast<const bf16x8*>(
        qp + (size_t)qrow * D_DIM + kc * 16 + h * 8);

  floatx16 ot[4];
#pragma unroll
  for (int d = 0; d < 4; ++d)
#pragma unroll
    for (int r = 0; r < 16; ++r) ot[d][r] = 0.f;
  float m_r = -1e30f, l_r = 0.f;

  const int cc = tid & 15;
  const int pr4 = (tid >> 4) * 4;
  const int ce = cc * 8;

  unsigned Rk[4];
#pragma unroll
  for (int x = 0; x < 4; ++x)
    Rk[x] = (unsigned)(h * 1024) +
            (((unsigned)(ql * 16)) ^ ((unsigned)h << 4) ^ ((unsigned)x << 5));
  const unsigned Rv0 = 32768u + (unsigned)(h * 2048) +
                       (((unsigned)(ql * 16)) ^ (((unsigned)(ql >> 3)) << 4));
  const unsigned Rv1 = Rv0 ^ 64u;
  const unsigned kx = ((unsigned)(cc & 7)) << 4;
  unsigned Wk_[4];
#pragma unroll
  for (int j = 0; j < 4; ++j)
    Wk_[j] = ((unsigned)(cc * 1024 + (pr4 + j) * 16)) ^ kx;
  unsigned Wv_[8];
  {
    unsigned vbase = 32768u + (unsigned)((pr4 >> 3) * 2048 + ce * 16 + (pr4 & 7) * 2);
#pragma unroll
    for (int e = 0; e < 8; ++e)
      Wv_[e] = vbase | (((unsigned)e << 4) ^ kx);
  }

  {
    const __bf16* kr = kp + (size_t)pr4 * D_DIM + ce;
    const __bf16* vr = vp + (size_t)pr4 * D_DIM + ce;
    bf16x8 kR[4];
    union { bf16x8 v8; unsigned short s[8]; } vR[4];
#pragma unroll
    for (int j = 0; j < 4; ++j) {
      kR[j] = *reinterpret_cast<const bf16x8*>(kr + j * D_DIM);
      vR[j].v8 = *reinterpret_cast<const bf16x8*>(vr + j * D_DIM);
    }
#pragma unroll
    for (int j = 0; j < 4; ++j)
      *reinterpret_cast<bf16x8*>(smem + Wk_[j]) = kR[j];
#pragma unroll
    for (int e = 0; e < 8; ++e) {
      uint2 w;
      w.x = (unsigned)vR[0].s[e] | ((unsigned)vR[1].s[e] << 16);
      w.y = (unsigned)vR[2].s[e] | ((unsigned)vR[3].s[e] << 16);
      *reinterpret_cast<uint2*>(smem + Wv_[e]) = w;
    }
  }

  const __bf16* krp = kp + ((size_t)KVB + pr4) * D_DIM + ce;
  const __bf16* vrp = vp + ((size_t)KVB + pr4) * D_DIM + ce;

#pragma unroll 2
  for (int t = 0; t < NKV; ++t) {
    const unsigned cb = (unsigned)(t & 1) * 16384u;
    const bool hn = (t + 1 < NKV);

    __syncthreads();

    bf16x8 kR[4];
    union { bf16x8 v8; unsigned short s[8]; } vR[4];
    if (hn) {
#pragma unroll
      for (int j = 0; j < 4; ++j) {
        kR[j] = *reinterpret_cast<const bf16x8*>(krp + j * D_DIM);
        vR[j].v8 = *reinterpret_cast<const bf16x8*>(vrp + j * D_DIM);
      }
      krp += (size_t)KVB * D_DIM;
      vrp += (size_t)KVB * D_DIM;
    }

    floatx16 st[2];
#pragma unroll
    for (int kvh = 0; kvh < 2; ++kvh)
#pragma unroll
      for (int r = 0; r < 16; ++r) st[kvh][r] = 0.f;
    __builtin_amdgcn_s_setprio(1);
#pragma unroll
    for (int kc = 0; kc < 8; ++kc) {
      bf16x8 kf0 = *reinterpret_cast<const bf16x8*>(
          smem + cb + Rk[kc & 3] + (unsigned)(kc * 2048));
      bf16x8 kf1 = *reinterpret_cast<const bf16x8*>(
          smem + cb + Rk[kc & 3] + (unsigned)(kc * 2048 + 512));
      st[0] = __builtin_amdgcn_mfma_f32_32x32x16_bf16(kf0, qf[kc], st[0], 0, 0, 0);
      st[1] = __builtin_amdgcn_mfma_f32_32x32x16_bf16(kf1, qf[kc], st[1], 0, 0, 0);
    }
    __builtin_amdgcn_s_setprio(0);

    if (hn) {
      const unsigned nb = cb ^ 16384u;
#pragma unroll
      for (int j = 0; j < 4; ++j)
        *reinterpret_cast<bf16x8*>(smem + nb + Wk_[j]) = kR[j];
#pragma unroll
      for (int e = 0; e < 8; ++e) {
        uint2 w;
        w.x = (unsigned)vR[0].s[e] | ((unsigned)vR[1].s[e] << 16);
        w.y = (unsigned)vR[2].s[e] | ((unsigned)vR[3].s[e] << 16);
        *reinterpret_cast<uint2*>(smem + nb + Wv_[e]) = w;
      }
    }

    float t8[8];
#pragma unroll
    for (int i = 0; i < 8; ++i)
      t8[i] = fmaxf(fmaxf(st[0][i], st[0][i + 8]), fmaxf(st[1][i], st[1][i + 8]));
    float pmax = fmaxf(fmaxf(fmaxf(t8[0], t8[4]), fmaxf(t8[1], t8[5])),
                       fmaxf(fmaxf(t8[2], t8[6]), fmaxf(t8[3], t8[7])));
    pmax = fmaxf(pmax, __shfl_xor(pmax, 32));
    if (!__all(pmax - m_r <= 8.0f)) {
      float mnew = fmaxf(m_r, pmax);
      float sc_f = __builtin_amdgcn_exp2f(m_r - mnew);
      m_r = mnew;
      l_r *= sc_f;
#pragma unroll
      for (int d = 0; d < 4; ++d)
#pragma unroll
        for (int r = 0; r < 16; ++r) ot[d][r] *= sc_f;
    }
#pragma unroll
    for (int kvh = 0; kvh < 2; ++kvh)
#pragma unroll
      for (int r = 0; r < 16; ++r)
        st[kvh][r] = __builtin_amdgcn_exp2f(st[kvh][r] - m_r);
    float s8[8];
#pragma unroll
    for (int i = 0; i < 8; ++i)
      s8[i] = (st[0][i] + st[0][i + 8]) + (st[1][i] + st[1][i + 8]);
    float psum = ((s8[0] + s8[4]) + (s8[1] + s8[5])) +
                 ((s8[2] + s8[6]) + (s8[3] + s8[7]));
    psum += __shfl_xor(psum, 32);
    l_r += psum;

#pragma unroll
    for (int ks = 0; ks < 4; ++ks) {
      const int kvh = ks >> 1;
      const int r2a = (2 * ks) & 3;
      const int r2b = r2a + 1;
      unsigned ua0 = pack2(st[kvh][r2a * 4 + 0], st[kvh][r2a * 4 + 1]);
      unsigned ua1 = pack2(st[kvh][r2a * 4 + 2], st[kvh][r2a * 4 + 3]);
      unsigned ub0 = pack2(st[kvh][r2b * 4 + 0], st[kvh][r2b * 4 + 1]);
      unsigned ub1 = pack2(st[kvh][r2b * 4 + 2], st[kvh][r2b * 4 + 3]);
      union { unsigned u[4]; bf16x8 v8; } pw;
#if __has_builtin(__builtin_amdgcn_permlane32_swap)
      {
        auto r0 = __builtin_amdgcn_permlane32_swap(ua0, ub0, false, false);
        auto r1 = __builtin_amdgcn_permlane32_swap(ua1, ub1, false, false);
        pw.u[0] = r0[0];
        pw.u[1] = r1[0];
        pw.u[2] = r0[1];
        pw.u[3] = r1[1];
      }
#else
      {
        unsigned a0x = __shfl_xor(ua0, 32), a1x = __shfl_xor(ua1, 32);
        unsigned b0x = __shfl_xor(ub0, 32), b1x = __shfl_xor(ub1, 32);
        pw.u[0] = h ? b0x : ua0;
        pw.u[1] = h ? b1x : ua1;
        pw.u[2] = h ? ub0 : a0x;
        pw.u[3] = h ? ub1 : a1x;
      }
#endif
      __builtin_amdgcn_s_setprio(1);
#pragma unroll
      for (int db = 0; db < 4; ++db) {
        const unsigned base = (db & 1) ? Rv1 : Rv0;
        bf16x8 vf = *reinterpret_cast<const bf16x8*>(
            smem + cb + base + (unsigned)(ks * 4096 + db * 512));
        ot[db] = __builtin_amdgcn_mfma_f32_32x32x16_bf16(vf, pw.v8, ot[db], 0, 0, 0);
      }
      __builtin_amdgcn_s_setprio(0);
    }
  }

  __syncthreads();
  const float inv_l = 1.0f / l_r;
  const int qloc = wave * 32 + ql;
#pragma unroll
  for (int db = 0; db < 4; ++db)
#pragma unroll
    for (int r = 0; r < 16; ++r) {
      int d = db * 32 + (r & 3) + 8 * (r >> 2) + 4 * h;
      *reinterpret_cast<__bf16*>(smem + swz(qloc, qloc * 256u + d * 2u)) =
          (__bf16)(ot[db][r] * inv_l);
    }
  __syncthreads();
#pragma unroll
  for (int it = 0; it < 8; ++it) {
    int r = tid >> 1;
    int c = (tid & 1) * 64 + it * 8;
    bf16x8 val = *reinterpret_cast<const bf16x8*>(smem + swz(r, r * 256u + c * 2u));
    *reinterpret_cast<bf16x8*>(op + (size_t)(qbase + r) * D_DIM + c) = val;
  }
}

// ---------------------------------------------------------------------------
extern "C" void kernel_launch(void* const* d_in, const int* in_sizes, int n_in,
                              void* d_out, int out_size, void* d_ws, size_t ws_size,
                              hipStream_t stream) {
  const float* query = (const float*)d_in[0];
  const float* key_  = (const float*)d_in[1];
  const float* value = (const float*)d_in[2];
  const float* Wq = (const float*)d_in[3];
  const float* bq = (const float*)d_in[4];
  const float* Wk = (const float*)d_in[5];
  const float* bk = (const float*)d_in[6];
  const float* Wv = (const float*)d_in[7];
  const float* bv = (const float*)d_in[8];
  const float* Wo = (const float*)d_in[9];
  const float* bo = (const float*)d_in[10];

  const size_t nelem = (size_t)NTOK * D_DIM;
  const float qscale = 0.1275174490036f;  // log2(e)/sqrt(128)
  dim3 blk(256);

  if (ws_size >= 3 * nelem * sizeof(__bf16)) {
    // fused path: q,k,v all in d_ws; d_out written by the fused epilogue.
    __bf16* vws = (__bf16*)d_ws;
    __bf16* qws = vws + nelem;
    __bf16* kws = qws + nelem;

    qkv_proj_kernel<<<dim3(NTOK / 256, 3), blk, 0, stream>>>(
        query, key_, value, Wq, Wk, Wv, bq, bk, bv, qws, kws, vws, qscale);

    attn_fused_kernel<<<dim3(32, 16), blk, 0, stream>>>(
        qws, kws, vws, Wo, bo, (float*)d_out);
  } else {
    // fallback (r13 path): q/k scratch inside d_out, aws in d_ws
    __bf16* vws = (__bf16*)d_ws;
    __bf16* aws = vws + nelem;
    __bf16* qws = (__bf16*)d_out;
    __bf16* kws = qws + nelem;

    qkv_proj_kernel<<<dim3(NTOK / 256, 3), blk, 0, stream>>>(
        query, key_, value, Wq, Wk, Wv, bq, bk, bv, qws, kws, vws, qscale);

    attn_kernel<<<dim3(32, 16), blk, 0, stream>>>(qws, kws, vws, aws);

    o_proj_kernel<<<NTOK / 256, blk, 0, stream>>>(aws, Wo, bo, (float*)d_out);
  }
}

// Round 16
// 126.129 us; speedup vs baseline: 1.3345x; 1.3345x over previous
//
#include <hip/hip_runtime.h>
#include <hip/hip_bf16.h>
#include <type_traits>
#include <math.h>

typedef __bf16 bf16x8 __attribute__((ext_vector_type(8)));
typedef float floatx4 __attribute__((ext_vector_type(4)));
typedef float floatx16 __attribute__((ext_vector_type(16)));

#define S_LEN 2048
#define D_DIM 128
#define NTOK (2 * 16 * 2048)  // B*H*S = 65536 rows
#define KVB 64
#define NKV (S_LEN / KVB)     // 32 kv tiles

// ---------------------------------------------------------------------------
// proj body: stages W once, then processes 4 chunks of 64 rows.
// ---------------------------------------------------------------------------
template <typename TIN, typename TOUT>
__device__ __forceinline__ void proj_body4(
    const TIN* __restrict__ x, const float* __restrict__ W,
    const float* __restrict__ b, TOUT* __restrict__ y, float out_scale,
    int chunk0, __bf16 (*Wl)[128]) {
  const int tid = threadIdx.x;
  const int wave = tid >> 6, lane = tid & 63;
  const int g = lane >> 4, lr = lane & 15;

  for (int it = 0; it < 16; ++it) {
    int lin = it * 1024 + tid * 4;
    float4 w4 = *reinterpret_cast<const float4*>(W + lin);
    int r = lin >> 7, c = lin & 127;
    Wl[r][c]     = (__bf16)w4.x;
    Wl[r][c + 1] = (__bf16)w4.y;
    Wl[r][c + 2] = (__bf16)w4.z;
    Wl[r][c + 3] = (__bf16)w4.w;
  }
  __syncthreads();

  float be[8];
#pragma unroll
  for (int nt = 0; nt < 8; ++nt) be[nt] = b[nt * 16 + lr];

  for (int ch = 0; ch < 4; ++ch) {
    const int rbase = (chunk0 + ch) * 64;
    const int arow = rbase + wave * 16 + lr;

    floatx4 acc[8];
#pragma unroll
    for (int i = 0; i < 8; ++i) acc[i] = floatx4{0.f, 0.f, 0.f, 0.f};

#pragma unroll
    for (int kc = 0; kc < 4; ++kc) {
      bf16x8 af;
      const TIN* xp = x + (size_t)arow * D_DIM + kc * 32 + g * 8;
      if constexpr (std::is_same<TIN, float>::value) {
        float4 f0 = *reinterpret_cast<const float4*>(xp);
        float4 f1 = *reinterpret_cast<const float4*>(xp + 4);
        af[0] = (__bf16)f0.x; af[1] = (__bf16)f0.y;
        af[2] = (__bf16)f0.z; af[3] = (__bf16)f0.w;
        af[4] = (__bf16)f1.x; af[5] = (__bf16)f1.y;
        af[6] = (__bf16)f1.z; af[7] = (__bf16)f1.w;
      } else {
        af = *reinterpret_cast<const bf16x8*>(xp);
      }
#pragma unroll
      for (int nt = 0; nt < 8; ++nt) {
        bf16x8 wf = *reinterpret_cast<const bf16x8*>(&Wl[nt * 16 + lr][kc * 32 + g * 8]);
        acc[nt] = __builtin_amdgcn_mfma_f32_16x16x32_bf16(af, wf, acc[nt], 0, 0, 0);
      }
    }

#pragma unroll
    for (int nt = 0; nt < 8; ++nt) {
      int e = nt * 16 + lr;
#pragma unroll
      for (int j = 0; j < 4; ++j) {
        int row = rbase + wave * 16 + g * 4 + j;
        float val = (acc[nt][j] + be[nt]) * out_scale;
        y[(size_t)row * D_DIM + e] = (TOUT)val;
      }
    }
  }
}

__global__ __launch_bounds__(256) void qkv_proj_kernel(
    const float* __restrict__ xq, const float* __restrict__ xk,
    const float* __restrict__ xv, const float* __restrict__ Wq,
    const float* __restrict__ Wk, const float* __restrict__ Wv,
    const float* __restrict__ bq, const float* __restrict__ bk,
    const float* __restrict__ bv, __bf16* yq, __bf16* yk, __bf16* yv,
    float qscale) {
  __shared__ alignas(16) __bf16 Wl[128][128];
  const int which = blockIdx.y;
  const float* x = which == 0 ? xq : which == 1 ? xk : xv;
  const float* W = which == 0 ? Wq : which == 1 ? Wk : Wv;
  const float* b = which == 0 ? bq : which == 1 ? bk : bv;
  __bf16* y = which == 0 ? yq : which == 1 ? yk : yv;
  float sc = which == 0 ? qscale : 1.0f;
  proj_body4<float, __bf16>(x, W, b, y, sc, blockIdx.x * 4, Wl);
}

__global__ __launch_bounds__(256) void o_proj_kernel(
    const __bf16* __restrict__ x, const float* __restrict__ W,
    const float* __restrict__ b, float* __restrict__ y) {
  __shared__ alignas(16) __bf16 Wl[128][128];
  proj_body4<__bf16, float>(x, W, b, y, 1.0f, blockIdx.x * 4, Wl);
}

// ---------------------------------------------------------------------------
// epilogue swizzle (O tile + Wo tile staging)
__device__ __forceinline__ unsigned swz(int row, unsigned byteoff) {
  return byteoff ^ (((unsigned)(row ^ (row >> 3)) & 7u) << 4);
}

__device__ __forceinline__ unsigned pack2(float lo, float hi) {
  union { __bf16 h[2]; unsigned u; } r;
  r.h[0] = (__bf16)lo; r.h[1] = (__bf16)hi;
  return r.u;
}

// ---------------------------------------------------------------------------
// attn_fused_kernel v16 = r14 (best: 94.8 us) + softmax-PV interleave:
// after the max tree + deferred rescale, the 32 exps are computed PER
// KS-GROUP inside the PV loop ({exp 8, pack, permlane, 4 MFMA} x 4), so
// group g's TRANS/VALU overlaps group g-1's MFMAs within the wave, and
// exp'd values feed pack2 directly (no st write-back). l-sum accumulated
// per group (reassociated fp add only).
// Everything else identical to r14: chunked conflict-free K/V LDS layouts,
// single barrier/tile, prefetch-after-barrier, write-early staging, swapped
// 32x32x16 QK^T, T13 defer-rescale, fused O-projection epilogue.
// ---------------------------------------------------------------------------
__global__ __launch_bounds__(256, 2) void attn_fused_kernel(
    const __bf16* __restrict__ q, const __bf16* __restrict__ k,
    const __bf16* __restrict__ v, const float* __restrict__ Wo,
    const float* __restrict__ bo, float* __restrict__ out) {
  __shared__ alignas(16) unsigned char smem[65536];

  const int tid = threadIdx.x;
  const int wave = tid >> 6, lane = tid & 63;
  const int ql = lane & 31;
  const int h = lane >> 5;

  const int bh = blockIdx.x;
  const int qbase = blockIdx.y * 128;
  const __bf16* qp = q + (size_t)bh * S_LEN * D_DIM;
  const __bf16* kp = k + (size_t)bh * S_LEN * D_DIM;
  const __bf16* vp = v + (size_t)bh * S_LEN * D_DIM;

  const int qrow = qbase + wave * 32 + ql;
  bf16x8 qf[8];
#pragma unroll
  for (int kc = 0; kc < 8; ++kc)
    qf[kc] = *reinterpret_cast<const bf16x8*>(
        qp + (size_t)qrow * D_DIM + kc * 16 + h * 8);

  floatx16 ot[4];
#pragma unroll
  for (int d = 0; d < 4; ++d)
#pragma unroll
    for (int r = 0; r < 16; ++r) ot[d][r] = 0.f;
  float m_r = -1e30f, l_r = 0.f;

  // staging map: 4 consecutive kv rows per thread
  const int cc = tid & 15;
  const int pr4 = (tid >> 4) * 4;
  const int ce = cc * 8;

  // ---- lane-resident LDS address bases (loop-invariant) ----
  unsigned Rk[4];
#pragma unroll
  for (int x = 0; x < 4; ++x)
    Rk[x] = (unsigned)(h * 1024) +
            (((unsigned)(ql * 16)) ^ ((unsigned)h << 4) ^ ((unsigned)x << 5));
  const unsigned Rv0 = 32768u + (unsigned)(h * 2048) +
                       (((unsigned)(ql * 16)) ^ (((unsigned)(ql >> 3)) << 4));
  const unsigned Rv1 = Rv0 ^ 64u;
  const unsigned kx = ((unsigned)(cc & 7)) << 4;
  unsigned Wk_[4];
#pragma unroll
  for (int j = 0; j < 4; ++j)
    Wk_[j] = ((unsigned)(cc * 1024 + (pr4 + j) * 16)) ^ kx;
  unsigned Wv_[8];
  {
    unsigned vbase = 32768u + (unsigned)((pr4 >> 3) * 2048 + ce * 16 + (pr4 & 7) * 2);
#pragma unroll
    for (int e = 0; e < 8; ++e)
      Wv_[e] = vbase | (((unsigned)e << 4) ^ kx);
  }

  // ---- prologue: stage tile 0 into buf 0 ----
  {
    const __bf16* kr = kp + (size_t)pr4 * D_DIM + ce;
    const __bf16* vr = vp + (size_t)pr4 * D_DIM + ce;
    bf16x8 kR[4];
    union { bf16x8 v8; unsigned short s[8]; } vR[4];
#pragma unroll
    for (int j = 0; j < 4; ++j) {
      kR[j] = *reinterpret_cast<const bf16x8*>(kr + j * D_DIM);
      vR[j].v8 = *reinterpret_cast<const bf16x8*>(vr + j * D_DIM);
    }
#pragma unroll
    for (int j = 0; j < 4; ++j)
      *reinterpret_cast<bf16x8*>(smem + Wk_[j]) = kR[j];
#pragma unroll
    for (int e = 0; e < 8; ++e) {
      uint2 w;
      w.x = (unsigned)vR[0].s[e] | ((unsigned)vR[1].s[e] << 16);
      w.y = (unsigned)vR[2].s[e] | ((unsigned)vR[3].s[e] << 16);
      *reinterpret_cast<uint2*>(smem + Wv_[e]) = w;
    }
  }

  const __bf16* krp = kp + ((size_t)KVB + pr4) * D_DIM + ce;
  const __bf16* vrp = vp + ((size_t)KVB + pr4) * D_DIM + ce;

#pragma unroll 2
  for (int t = 0; t < NKV; ++t) {
    const unsigned cb = (unsigned)(t & 1) * 16384u;
    const bool hn = (t + 1 < NKV);

    __syncthreads();  // buf[cur] staged; all waves done with body t-1

    bf16x8 kR[4];
    union { bf16x8 v8; unsigned short s[8]; } vR[4];
    if (hn) {  // issue next-tile global loads (after barrier: no drain)
#pragma unroll
      for (int j = 0; j < 4; ++j) {
        kR[j] = *reinterpret_cast<const bf16x8*>(krp + j * D_DIM);
        vR[j].v8 = *reinterpret_cast<const bf16x8*>(vrp + j * D_DIM);
      }
      krp += (size_t)KVB * D_DIM;
      vrp += (size_t)KVB * D_DIM;
    }

    // ---- QK^T: S^T[kv][q] ----
    floatx16 st[2];
#pragma unroll
    for (int kvh = 0; kvh < 2; ++kvh)
#pragma unroll
      for (int r = 0; r < 16; ++r) st[kvh][r] = 0.f;
    __builtin_amdgcn_s_setprio(1);
#pragma unroll
    for (int kc = 0; kc < 8; ++kc) {
      bf16x8 kf0 = *reinterpret_cast<const bf16x8*>(
          smem + cb + Rk[kc & 3] + (unsigned)(kc * 2048));
      bf16x8 kf1 = *reinterpret_cast<const bf16x8*>(
          smem + cb + Rk[kc & 3] + (unsigned)(kc * 2048 + 512));
      st[0] = __builtin_amdgcn_mfma_f32_32x32x16_bf16(kf0, qf[kc], st[0], 0, 0, 0);
      st[1] = __builtin_amdgcn_mfma_f32_32x32x16_bf16(kf1, qf[kc], st[1], 0, 0, 0);
    }
    __builtin_amdgcn_s_setprio(0);

    // ---- write staged tile t+1 into buf[nxt] EARLY ----
    if (hn) {
      const unsigned nb = cb ^ 16384u;
#pragma unroll
      for (int j = 0; j < 4; ++j)
        *reinterpret_cast<bf16x8*>(smem + nb + Wk_[j]) = kR[j];
#pragma unroll
      for (int e = 0; e < 8; ++e) {
        uint2 w;
        w.x = (unsigned)vR[0].s[e] | ((unsigned)vR[1].s[e] << 16);
        w.y = (unsigned)vR[2].s[e] | ((unsigned)vR[3].s[e] << 16);
        *reinterpret_cast<uint2*>(smem + nb + Wv_[e]) = w;
      }
    }

    // ---- max tree + T13 defer-rescale (exps deferred into PV groups) ----
    float t8[8];
#pragma unroll
    for (int i = 0; i < 8; ++i)
      t8[i] = fmaxf(fmaxf(st[0][i], st[0][i + 8]), fmaxf(st[1][i], st[1][i + 8]));
    float pmax = fmaxf(fmaxf(fmaxf(t8[0], t8[4]), fmaxf(t8[1], t8[5])),
                       fmaxf(fmaxf(t8[2], t8[6]), fmaxf(t8[3], t8[7])));
    pmax = fmaxf(pmax, __shfl_xor(pmax, 32));
    if (!__all(pmax - m_r <= 8.0f)) {
      float mnew = fmaxf(m_r, pmax);
      float sc_f = __builtin_amdgcn_exp2f(m_r - mnew);
      m_r = mnew;
      l_r *= sc_f;
#pragma unroll
      for (int d = 0; d < 4; ++d)
#pragma unroll
        for (int r = 0; r < 16; ++r) ot[d][r] *= sc_f;
    }

    // ---- PV with per-group exp (group g VALU overlaps group g-1 MFMA) ----
    float lacc = 0.f;
#pragma unroll
    for (int ks = 0; ks < 4; ++ks) {
      const int kvh = ks >> 1;
      const int r2a = (2 * ks) & 3;
      const int r2b = r2a + 1;
      float e0 = __builtin_amdgcn_exp2f(st[kvh][r2a * 4 + 0] - m_r);
      float e1 = __builtin_amdgcn_exp2f(st[kvh][r2a * 4 + 1] - m_r);
      float e2 = __builtin_amdgcn_exp2f(st[kvh][r2a * 4 + 2] - m_r);
      float e3 = __builtin_amdgcn_exp2f(st[kvh][r2a * 4 + 3] - m_r);
      float e4 = __builtin_amdgcn_exp2f(st[kvh][r2b * 4 + 0] - m_r);
      float e5 = __builtin_amdgcn_exp2f(st[kvh][r2b * 4 + 1] - m_r);
      float e6 = __builtin_amdgcn_exp2f(st[kvh][r2b * 4 + 2] - m_r);
      float e7 = __builtin_amdgcn_exp2f(st[kvh][r2b * 4 + 3] - m_r);
      lacc += ((e0 + e4) + (e1 + e5)) + ((e2 + e6) + (e3 + e7));
      unsigned ua0 = pack2(e0, e1);
      unsigned ua1 = pack2(e2, e3);
      unsigned ub0 = pack2(e4, e5);
      unsigned ub1 = pack2(e6, e7);
      union { unsigned u[4]; bf16x8 v8; } pw;
#if __has_builtin(__builtin_amdgcn_permlane32_swap)
      {
        auto r0 = __builtin_amdgcn_permlane32_swap(ua0, ub0, false, false);
        auto r1 = __builtin_amdgcn_permlane32_swap(ua1, ub1, false, false);
        pw.u[0] = r0[0];
        pw.u[1] = r1[0];
        pw.u[2] = r0[1];
        pw.u[3] = r1[1];
      }
#else
      {
        unsigned a0x = __shfl_xor(ua0, 32), a1x = __shfl_xor(ua1, 32);
        unsigned b0x = __shfl_xor(ub0, 32), b1x = __shfl_xor(ub1, 32);
        pw.u[0] = h ? b0x : ua0;
        pw.u[1] = h ? b1x : ua1;
        pw.u[2] = h ? ub0 : a0x;
        pw.u[3] = h ? ub1 : a1x;
      }
#endif
      __builtin_amdgcn_s_setprio(1);
#pragma unroll
      for (int db = 0; db < 4; ++db) {
        const unsigned base = (db & 1) ? Rv1 : Rv0;
        bf16x8 vf = *reinterpret_cast<const bf16x8*>(
            smem + cb + base + (unsigned)(ks * 4096 + db * 512));
        ot[db] = __builtin_amdgcn_mfma_f32_32x32x16_bf16(vf, pw.v8, ot[db], 0, 0, 0);
      }
      __builtin_amdgcn_s_setprio(0);
    }
    float psum = lacc + __shfl_xor(lacc, 32);
    l_r += psum;
  }

  // ==== fused epilogue: O -> LDS; Wo -> LDS; proj; write fp32 d_out ====
  __syncthreads();  // all waves done with K/V LDS

  // (a) O^T -> LDS[0..32K) as row-major bf16 (divided by l), swizzled
  {
    const float inv_l = 1.0f / l_r;
    const int qloc = wave * 32 + ql;
#pragma unroll
    for (int db = 0; db < 4; ++db)
#pragma unroll
      for (int r = 0; r < 16; ++r) {
        int d = db * 32 + (r & 3) + 8 * (r >> 2) + 4 * h;
        *reinterpret_cast<__bf16*>(smem + swz(qloc, qloc * 256u + d * 2u)) =
            (__bf16)(ot[db][r] * inv_l);
      }
  }
  // (b) Wo fp32 -> LDS[32K..64K) as bf16, swizzled rows
  for (int it = 0; it < 16; ++it) {
    int lin = it * 1024 + tid * 4;
    float4 w4 = *reinterpret_cast<const float4*>(Wo + lin);
    int r = lin >> 7, c = lin & 127;
    unsigned off = 32768u + swz(r, (unsigned)(r * 256 + c * 2));
    __bf16 b4[4] = {(__bf16)w4.x, (__bf16)w4.y, (__bf16)w4.z, (__bf16)w4.w};
    *reinterpret_cast<uint2*>(smem + off) = *reinterpret_cast<uint2*>(b4);
  }
  __syncthreads();

  // (c) proj: out[q][e] = O[q][:] . Wo[e][:] + bo[e]
  const int g4 = lane >> 4;
  const int lr = lane & 15;
  float be[8];
#pragma unroll
  for (int nt = 0; nt < 8; ++nt) be[nt] = bo[nt * 16 + lr];

#pragma unroll
  for (int rt = 0; rt < 2; ++rt) {
    const int arow = wave * 32 + rt * 16 + lr;
    floatx4 acc[8];
#pragma unroll
    for (int i = 0; i < 8; ++i) acc[i] = floatx4{0.f, 0.f, 0.f, 0.f};
#pragma unroll
    for (int kc = 0; kc < 4; ++kc) {
      bf16x8 af = *reinterpret_cast<const bf16x8*>(
          smem + swz(arow, (unsigned)(arow * 256 + (kc * 32 + g4 * 8) * 2)));
#pragma unroll
      for (int nt = 0; nt < 8; ++nt) {
        int wrow = nt * 16 + lr;
        bf16x8 wf = *reinterpret_cast<const bf16x8*>(
            smem + 32768u + swz(wrow, (unsigned)(wrow * 256 + (kc * 32 + g4 * 8) * 2)));
        acc[nt] = __builtin_amdgcn_mfma_f32_16x16x32_bf16(af, wf, acc[nt], 0, 0, 0);
      }
    }
#pragma unroll
    for (int nt = 0; nt < 8; ++nt) {
      int e = nt * 16 + lr;
#pragma unroll
      for (int j = 0; j < 4; ++j) {
        int row = qbase + wave * 32 + rt * 16 + g4 * 4 + j;
        out[((size_t)bh * S_LEN + row) * D_DIM + e] = acc[nt][j] + be[nt];
      }
    }
  }
}

// ---------------------------------------------------------------------------
// attn_kernel (fallback path, r13-proven; only used if ws_size too small)
// ---------------------------------------------------------------------------
__global__ __launch_bounds__(256, 2) void attn_kernel(
    const __bf16* __restrict__ q, const __bf16* __restrict__ k,
    const __bf16* __restrict__ v, __bf16* __restrict__ o) {
  __shared__ alignas(16) unsigned char smem[65536];

  const int tid = threadIdx.x;
  const int wave = tid >> 6, lane = tid & 63;
  const int ql = lane & 31;
  const int h = lane >> 5;

  const int bh = blockIdx.x;
  const int qbase = blockIdx.y * 128;
  const __bf16* qp = q + (size_t)bh * S_LEN * D_DIM;
  const __bf16* kp = k + (size_t)bh * S_LEN * D_DIM;
  const __bf16* vp = v + (size_t)bh * S_LEN * D_DIM;
  __bf16* op = o + (size_t)bh * S_LEN * D_DIM;

  const int qrow = qbase + wave * 32 + ql;
  bf16x8 qf[8];
#pragma unroll
  for (int kc = 0; kc < 8; ++kc)
    qf[kc] = *reinterpret_cast<const bf16x8*>(
        qp + (size_t)qrow * D_DIM + kc * 16 + h * 8);

  floatx16 ot[4];
#pragma unroll
  for (int d = 0; d < 4; ++d)
#pragma unroll
    for (int r = 0; r < 16; ++r) ot[d][r] = 0.f;
  float m_r = -1e30f, l_r = 0.f;

  const int cc = tid & 15;
  const int pr4 = (tid >> 4) * 4;
  const int ce = cc * 8;

  unsigned Rk[4];
#pragma unroll
  for (int x = 0; x < 4; ++x)
    Rk[x] = (unsigned)(h * 1024) +
            (((unsigned)(ql * 16)) ^ ((unsigned)h << 4) ^ ((unsigned)x << 5));
  const unsigned Rv0 = 32768u + (unsigned)(h * 2048) +
                       (((unsigned)(ql * 16)) ^ (((unsigned)(ql >> 3)) << 4));
  const unsigned Rv1 = Rv0 ^ 64u;
  const unsigned kx = ((unsigned)(cc & 7)) << 4;
  unsigned Wk_[4];
#pragma unroll
  for (int j = 0; j < 4; ++j)
    Wk_[j] = ((unsigned)(cc * 1024 + (pr4 + j) * 16)) ^ kx;
  unsigned Wv_[8];
  {
    unsigned vbase = 32768u + (unsigned)((pr4 >> 3) * 2048 + ce * 16 + (pr4 & 7) * 2);
#pragma unroll
    for (int e = 0; e < 8; ++e)
      Wv_[e] = vbase | (((unsigned)e << 4) ^ kx);
  }

  {
    const __bf16* kr = kp + (size_t)pr4 * D_DIM + ce;
    const __bf16* vr = vp + (size_t)pr4 * D_DIM + ce;
    bf16x8 kR[4];
    union { bf16x8 v8; unsigned short s[8]; } vR[4];
#pragma unroll
    for (int j = 0; j < 4; ++j) {
      kR[j] = *reinterpret_cast<const bf16x8*>(kr + j * D_DIM);
      vR[j].v8 = *reinterpret_cast<const bf16x8*>(vr + j * D_DIM);
    }
#pragma unroll
    for (int j = 0; j < 4; ++j)
      *reinterpret_cast<bf16x8*>(smem + Wk_[j]) = kR[j];
#pragma unroll
    for (int e = 0; e < 8; ++e) {
      uint2 w;
      w.x = (unsigned)vR[0].s[e] | ((unsigned)vR[1].s[e] << 16);
      w.y = (unsigned)vR[2].s[e] | ((unsigned)vR[3].s[e] << 16);
      *reinterpret_cast<uint2*>(smem + Wv_[e]) = w;
    }
  }

  const __bf16* krp = kp + ((size_t)KVB + pr4) * D_DIM + ce;
  const __bf16* vrp = vp + ((size_t)KVB + pr4) * D_DIM + ce;

#pragma unroll 2
  for (int t = 0; t < NKV; ++t) {
    const unsigned cb = (unsigned)(t & 1) * 16384u;
    const bool hn = (t + 1 < NKV);

    __syncthreads();

    bf16x8 kR[4];
    union { bf16x8 v8; unsigned short s[8]; } vR[4];
    if (hn) {
#pragma unroll
      for (int j = 0; j < 4; ++j) {
        kR[j] = *reinterpret_cast<const bf16x8*>(krp + j * D_DIM);
        vR[j].v8 = *reinterpret_cast<const bf16x8*>(vrp + j * D_DIM);
      }
      krp += (size_t)KVB * D_DIM;
      vrp += (size_t)KVB * D_DIM;
    }

    floatx16 st[2];
#pragma unroll
    for (int kvh = 0; kvh < 2; ++kvh)
#pragma unroll
      for (int r = 0; r < 16; ++r) st[kvh][r] = 0.f;
    __builtin_amdgcn_s_setprio(1);
#pragma unroll
    for (int kc = 0; kc < 8; ++kc) {
      bf16x8 kf0 = *reinterpret_cast<const bf16x8*>(
          smem + cb + Rk[kc & 3] + (unsigned)(kc * 2048));
      bf16x8 kf1 = *reinterpret_cast<const bf16x8*>(
          smem + cb + Rk[kc & 3] + (unsigned)(kc * 2048 + 512));
      st[0] = __builtin_amdgcn_mfma_f32_32x32x16_bf16(kf0, qf[kc], st[0], 0, 0, 0);
      st[1] = __builtin_amdgcn_mfma_f32_32x32x16_bf16(kf1, qf[kc], st[1], 0, 0, 0);
    }
    __builtin_amdgcn_s_setprio(0);

    if (hn) {
      const unsigned nb = cb ^ 16384u;
#pragma unroll
      for (int j = 0; j < 4; ++j)
        *reinterpret_cast<bf16x8*>(smem + nb + Wk_[j]) = kR[j];
#pragma unroll
      for (int e = 0; e < 8; ++e) {
        uint2 w;
        w.x = (unsigned)vR[0].s[e] | ((unsigned)vR[1].s[e] << 16);
        w.y = (unsigned)vR[2].s[e] | ((unsigned)vR[3].s[e] << 16);
        *reinterpret_cast<uint2*>(smem + nb + Wv_[e]) = w;
      }
    }

    float t8[8];
#pragma unroll
    for (int i = 0; i < 8; ++i)
      t8[i] = fmaxf(fmaxf(st[0][i], st[0][i + 8]), fmaxf(st[1][i], st[1][i + 8]));
    float pmax = fmaxf(fmaxf(fmaxf(t8[0], t8[4]), fmaxf(t8[1], t8[5])),
                       fmaxf(fmaxf(t8[2], t8[6]), fmaxf(t8[3], t8[7])));
    pmax = fmaxf(pmax, __shfl_xor(pmax, 32));
    if (!__all(pmax - m_r <= 8.0f)) {
      float mnew = fmaxf(m_r, pmax);
      float sc_f = __builtin_amdgcn_exp2f(m_r - mnew);
      m_r = mnew;
      l_r *= sc_f;
#pragma unroll
      for (int d = 0; d < 4; ++d)
#pragma unroll
        for (int r = 0; r < 16; ++r) ot[d][r] *= sc_f;
    }
#pragma unroll
    for (int kvh = 0; kvh < 2; ++kvh)
#pragma unroll
      for (int r = 0; r < 16; ++r)
        st[kvh][r] = __builtin_amdgcn_exp2f(st[kvh][r] - m_r);
    float s8[8];
#pragma unroll
    for (int i = 0; i < 8; ++i)
      s8[i] = (st[0][i] + st[0][i + 8]) + (st[1][i] + st[1][i + 8]);
    float psum = ((s8[0] + s8[4]) + (s8[1] + s8[5])) +
                 ((s8[2] + s8[6]) + (s8[3] + s8[7]));
    psum += __shfl_xor(psum, 32);
    l_r += psum;

#pragma unroll
    for (int ks = 0; ks < 4; ++ks) {
      const int kvh = ks >> 1;
      const int r2a = (2 * ks) & 3;
      const int r2b = r2a + 1;
      unsigned ua0 = pack2(st[kvh][r2a * 4 + 0], st[kvh][r2a * 4 + 1]);
      unsigned ua1 = pack2(st[kvh][r2a * 4 + 2], st[kvh][r2a * 4 + 3]);
      unsigned ub0 = pack2(st[kvh][r2b * 4 + 0], st[kvh][r2b * 4 + 1]);
      unsigned ub1 = pack2(st[kvh][r2b * 4 + 2], st[kvh][r2b * 4 + 3]);
      union { unsigned u[4]; bf16x8 v8; } pw;
#if __has_builtin(__builtin_amdgcn_permlane32_swap)
      {
        auto r0 = __builtin_amdgcn_permlane32_swap(ua0, ub0, false, false);
        auto r1 = __builtin_amdgcn_permlane32_swap(ua1, ub1, false, false);
        pw.u[0] = r0[0];
        pw.u[1] = r1[0];
        pw.u[2] = r0[1];
        pw.u[3] = r1[1];
      }
#else
      {
        unsigned a0x = __shfl_xor(ua0, 32), a1x = __shfl_xor(ua1, 32);
        unsigned b0x = __shfl_xor(ub0, 32), b1x = __shfl_xor(ub1, 32);
        pw.u[0] = h ? b0x : ua0;
        pw.u[1] = h ? b1x : ua1;
        pw.u[2] = h ? ub0 : a0x;
        pw.u[3] = h ? ub1 : a1x;
      }
#endif
      __builtin_amdgcn_s_setprio(1);
#pragma unroll
      for (int db = 0; db < 4; ++db) {
        const unsigned base = (db & 1) ? Rv1 : Rv0;
        bf16x8 vf = *reinterpret_cast<const bf16x8*>(
            smem + cb + base + (unsigned)(ks * 4096 + db * 512));
        ot[db] = __builtin_amdgcn_mfma_f32_32x32x16_bf16(vf, pw.v8, ot[db], 0, 0, 0);
      }
      __builtin_amdgcn_s_setprio(0);
    }
  }

  __syncthreads();
  const float inv_l = 1.0f / l_r;
  const int qloc = wave * 32 + ql;
#pragma unroll
  for (int db = 0; db < 4; ++db)
#pragma unroll
    for (int r = 0; r < 16; ++r) {
      int d = db * 32 + (r & 3) + 8 * (r >> 2) + 4 * h;
      *reinterpret_cast<__bf16*>(smem + swz(qloc, qloc * 256u + d * 2u)) =
          (__bf16)(ot[db][r] * inv_l);
    }
  __syncthreads();
#pragma unroll
  for (int it = 0; it < 8; ++it) {
    int r = tid >> 1;
    int c = (tid & 1) * 64 + it * 8;
    bf16x8 val = *reinterpret_cast<const bf16x8*>(smem + swz(r, r * 256u + c * 2u));
    *reinterpret_cast<bf16x8*>(op + (size_t)(qbase + r) * D_DIM + c) = val;
  }
}

// ---------------------------------------------------------------------------
extern "C" void kernel_launch(void* const* d_in, const int* in_sizes, int n_in,
                              void* d_out, int out_size, void* d_ws, size_t ws_size,
                              hipStream_t stream) {
  const float* query = (const float*)d_in[0];
  const float* key_  = (const float*)d_in[1];
  const float* value = (const float*)d_in[2];
  const float* Wq = (const float*)d_in[3];
  const float* bq = (const float*)d_in[4];
  const float* Wk = (const float*)d_in[5];
  const float* bk = (const float*)d_in[6];
  const float* Wv = (const float*)d_in[7];
  const float* bv = (const float*)d_in[8];
  const float* Wo = (const float*)d_in[9];
  const float* bo = (const float*)d_in[10];

  const size_t nelem = (size_t)NTOK * D_DIM;
  const float qscale = 0.1275174490036f;  // log2(e)/sqrt(128)
  dim3 blk(256);

  if (ws_size >= 3 * nelem * sizeof(__bf16)) {
    // fused path: q,k,v all in d_ws; d_out written by the fused epilogue.
    __bf16* vws = (__bf16*)d_ws;
    __bf16* qws = vws + nelem;
    __bf16* kws = qws + nelem;

    qkv_proj_kernel<<<dim3(NTOK / 256, 3), blk, 0, stream>>>(
        query, key_, value, Wq, Wk, Wv, bq, bk, bv, qws, kws, vws, qscale);

    attn_fused_kernel<<<dim3(32, 16), blk, 0, stream>>>(
        qws, kws, vws, Wo, bo, (float*)d_out);
  } else {
    // fallback (r13 path): q/k scratch inside d_out, aws in d_ws
    __bf16* vws = (__bf16*)d_ws;
    __bf16* aws = vws + nelem;
    __bf16* qws = (__bf16*)d_out;
    __bf16* kws = qws + nelem;

    qkv_proj_kernel<<<dim3(NTOK / 256, 3), blk, 0, stream>>>(
        query, key_, value, Wq, Wk, Wv, bq, bk, bv, qws, kws, vws, qscale);

    attn_kernel<<<dim3(32, 16), blk, 0, stream>>>(qws, kws, vws, aws);

    o_proj_kernel<<<NTOK / 256, blk, 0, stream>>>(aws, Wo, bo, (float*)d_out);
  }
}

// Round 17
// 123.486 us; speedup vs baseline: 1.3630x; 1.0214x over previous
//
#include <hip/hip_runtime.h>
#include <hip/hip_bf16.h>
#include <type_traits>
#include <math.h>

typedef __bf16 bf16x8 __attribute__((ext_vector_type(8)));
typedef float floatx4 __attribute__((ext_vector_type(4)));
typedef float floatx16 __attribute__((ext_vector_type(16)));

#define S_LEN 2048
#define D_DIM 128
#define NTOK (2 * 16 * 2048)  // B*H*S = 65536 rows
#define KVB 64
#define NKV (S_LEN / KVB)     // 32 kv tiles

// ---------------------------------------------------------------------------
// proj body: stages W once, then processes 4 chunks of 64 rows.
// ---------------------------------------------------------------------------
template <typename TIN, typename TOUT>
__device__ __forceinline__ void proj_body4(
    const TIN* __restrict__ x, const float* __restrict__ W,
    const float* __restrict__ b, TOUT* __restrict__ y, float out_scale,
    int chunk0, __bf16 (*Wl)[128]) {
  const int tid = threadIdx.x;
  const int wave = tid >> 6, lane = tid & 63;
  const int g = lane >> 4, lr = lane & 15;

  for (int it = 0; it < 16; ++it) {
    int lin = it * 1024 + tid * 4;
    float4 w4 = *reinterpret_cast<const float4*>(W + lin);
    int r = lin >> 7, c = lin & 127;
    Wl[r][c]     = (__bf16)w4.x;
    Wl[r][c + 1] = (__bf16)w4.y;
    Wl[r][c + 2] = (__bf16)w4.z;
    Wl[r][c + 3] = (__bf16)w4.w;
  }
  __syncthreads();

  float be[8];
#pragma unroll
  for (int nt = 0; nt < 8; ++nt) be[nt] = b[nt * 16 + lr];

  for (int ch = 0; ch < 4; ++ch) {
    const int rbase = (chunk0 + ch) * 64;
    const int arow = rbase + wave * 16 + lr;

    floatx4 acc[8];
#pragma unroll
    for (int i = 0; i < 8; ++i) acc[i] = floatx4{0.f, 0.f, 0.f, 0.f};

#pragma unroll
    for (int kc = 0; kc < 4; ++kc) {
      bf16x8 af;
      const TIN* xp = x + (size_t)arow * D_DIM + kc * 32 + g * 8;
      if constexpr (std::is_same<TIN, float>::value) {
        float4 f0 = *reinterpret_cast<const float4*>(xp);
        float4 f1 = *reinterpret_cast<const float4*>(xp + 4);
        af[0] = (__bf16)f0.x; af[1] = (__bf16)f0.y;
        af[2] = (__bf16)f0.z; af[3] = (__bf16)f0.w;
        af[4] = (__bf16)f1.x; af[5] = (__bf16)f1.y;
        af[6] = (__bf16)f1.z; af[7] = (__bf16)f1.w;
      } else {
        af = *reinterpret_cast<const bf16x8*>(xp);
      }
#pragma unroll
      for (int nt = 0; nt < 8; ++nt) {
        bf16x8 wf = *reinterpret_cast<const bf16x8*>(&Wl[nt * 16 + lr][kc * 32 + g * 8]);
        acc[nt] = __builtin_amdgcn_mfma_f32_16x16x32_bf16(af, wf, acc[nt], 0, 0, 0);
      }
    }

#pragma unroll
    for (int nt = 0; nt < 8; ++nt) {
      int e = nt * 16 + lr;
#pragma unroll
      for (int j = 0; j < 4; ++j) {
        int row = rbase + wave * 16 + g * 4 + j;
        float val = (acc[nt][j] + be[nt]) * out_scale;
        y[(size_t)row * D_DIM + e] = (TOUT)val;
      }
    }
  }
}

__global__ __launch_bounds__(256) void qkv_proj_kernel(
    const float* __restrict__ xq, const float* __restrict__ xk,
    const float* __restrict__ xv, const float* __restrict__ Wq,
    const float* __restrict__ Wk, const float* __restrict__ Wv,
    const float* __restrict__ bq, const float* __restrict__ bk,
    const float* __restrict__ bv, __bf16* yq, __bf16* yk, __bf16* yv,
    float qscale) {
  __shared__ alignas(16) __bf16 Wl[128][128];
  const int which = blockIdx.y;
  const float* x = which == 0 ? xq : which == 1 ? xk : xv;
  const float* W = which == 0 ? Wq : which == 1 ? Wk : Wv;
  const float* b = which == 0 ? bq : which == 1 ? bk : bv;
  __bf16* y = which == 0 ? yq : which == 1 ? yk : yv;
  float sc = which == 0 ? qscale : 1.0f;
  proj_body4<float, __bf16>(x, W, b, y, sc, blockIdx.x * 4, Wl);
}

__global__ __launch_bounds__(256) void o_proj_kernel(
    const __bf16* __restrict__ x, const float* __restrict__ W,
    const float* __restrict__ b, float* __restrict__ y) {
  __shared__ alignas(16) __bf16 Wl[128][128];
  proj_body4<__bf16, float>(x, W, b, y, 1.0f, blockIdx.x * 4, Wl);
}

// ---------------------------------------------------------------------------
// epilogue swizzle (O tile + Wo tile staging)
__device__ __forceinline__ unsigned swz(int row, unsigned byteoff) {
  return byteoff ^ (((unsigned)(row ^ (row >> 3)) & 7u) << 4);
}

__device__ __forceinline__ unsigned pack2(float lo, float hi) {
  union { __bf16 h[2]; unsigned u; } r;
  r.h[0] = (__bf16)lo; r.h[1] = (__bf16)hi;
  return r.u;
}

// ---------------------------------------------------------------------------
// attn_fused_kernel (r14, best measured: attn 94.8 us, total 123.5 us):
// r13 attn k-loop + fused O-projection epilogue.
//
// K-loop: chunked conflict-free LDS layouts, single barrier/tile,
// prefetch-after-barrier, write-early staging, swapped 32x32x16 QK^T,
// in-register exp2-domain softmax, T13 defer-rescale, in-register P^T via
// permlane32_swap.
//
// Fused epilogue: O^T -> LDS[0..32K) row-major bf16 (swizzled, /l);
// Wo fp32 -> LDS[32K..64K) bf16 (swizzled); barrier; per wave proj_body-
// style 64x MFMA 16x16x32; write fp32 d_out directly. Eliminates the
// separate o_proj kernel (launch + 16.8 MB re-read). REQUIRES q/k NOT
// aliased into d_out -> q,k,v all in d_ws; fallback otherwise.
// ---------------------------------------------------------------------------
__global__ __launch_bounds__(256, 2) void attn_fused_kernel(
    const __bf16* __restrict__ q, const __bf16* __restrict__ k,
    const __bf16* __restrict__ v, const float* __restrict__ Wo,
    const float* __restrict__ bo, float* __restrict__ out) {
  __shared__ alignas(16) unsigned char smem[65536];

  const int tid = threadIdx.x;
  const int wave = tid >> 6, lane = tid & 63;
  const int ql = lane & 31;
  const int h = lane >> 5;

  const int bh = blockIdx.x;
  const int qbase = blockIdx.y * 128;
  const __bf16* qp = q + (size_t)bh * S_LEN * D_DIM;
  const __bf16* kp = k + (size_t)bh * S_LEN * D_DIM;
  const __bf16* vp = v + (size_t)bh * S_LEN * D_DIM;

  const int qrow = qbase + wave * 32 + ql;
  bf16x8 qf[8];
#pragma unroll
  for (int kc = 0; kc < 8; ++kc)
    qf[kc] = *reinterpret_cast<const bf16x8*>(
        qp + (size_t)qrow * D_DIM + kc * 16 + h * 8);

  floatx16 ot[4];
#pragma unroll
  for (int d = 0; d < 4; ++d)
#pragma unroll
    for (int r = 0; r < 16; ++r) ot[d][r] = 0.f;
  float m_r = -1e30f, l_r = 0.f;

  // staging map: 4 consecutive kv rows per thread
  const int cc = tid & 15;
  const int pr4 = (tid >> 4) * 4;
  const int ce = cc * 8;

  // ---- lane-resident LDS address bases (loop-invariant) ----
  unsigned Rk[4];
#pragma unroll
  for (int x = 0; x < 4; ++x)
    Rk[x] = (unsigned)(h * 1024) +
            (((unsigned)(ql * 16)) ^ ((unsigned)h << 4) ^ ((unsigned)x << 5));
  const unsigned Rv0 = 32768u + (unsigned)(h * 2048) +
                       (((unsigned)(ql * 16)) ^ (((unsigned)(ql >> 3)) << 4));
  const unsigned Rv1 = Rv0 ^ 64u;
  const unsigned kx = ((unsigned)(cc & 7)) << 4;
  unsigned Wk_[4];
#pragma unroll
  for (int j = 0; j < 4; ++j)
    Wk_[j] = ((unsigned)(cc * 1024 + (pr4 + j) * 16)) ^ kx;
  unsigned Wv_[8];
  {
    unsigned vbase = 32768u + (unsigned)((pr4 >> 3) * 2048 + ce * 16 + (pr4 & 7) * 2);
#pragma unroll
    for (int e = 0; e < 8; ++e)
      Wv_[e] = vbase | (((unsigned)e << 4) ^ kx);
  }

  // ---- prologue: stage tile 0 into buf 0 ----
  {
    const __bf16* kr = kp + (size_t)pr4 * D_DIM + ce;
    const __bf16* vr = vp + (size_t)pr4 * D_DIM + ce;
    bf16x8 kR[4];
    union { bf16x8 v8; unsigned short s[8]; } vR[4];
#pragma unroll
    for (int j = 0; j < 4; ++j) {
      kR[j] = *reinterpret_cast<const bf16x8*>(kr + j * D_DIM);
      vR[j].v8 = *reinterpret_cast<const bf16x8*>(vr + j * D_DIM);
    }
#pragma unroll
    for (int j = 0; j < 4; ++j)
      *reinterpret_cast<bf16x8*>(smem + Wk_[j]) = kR[j];
#pragma unroll
    for (int e = 0; e < 8; ++e) {
      uint2 w;
      w.x = (unsigned)vR[0].s[e] | ((unsigned)vR[1].s[e] << 16);
      w.y = (unsigned)vR[2].s[e] | ((unsigned)vR[3].s[e] << 16);
      *reinterpret_cast<uint2*>(smem + Wv_[e]) = w;
    }
  }

  const __bf16* krp = kp + ((size_t)KVB + pr4) * D_DIM + ce;
  const __bf16* vrp = vp + ((size_t)KVB + pr4) * D_DIM + ce;

#pragma unroll 2
  for (int t = 0; t < NKV; ++t) {
    const unsigned cb = (unsigned)(t & 1) * 16384u;
    const bool hn = (t + 1 < NKV);

    __syncthreads();  // buf[cur] staged; all waves done with body t-1

    bf16x8 kR[4];
    union { bf16x8 v8; unsigned short s[8]; } vR[4];
    if (hn) {  // issue next-tile global loads (after barrier: no drain)
#pragma unroll
      for (int j = 0; j < 4; ++j) {
        kR[j] = *reinterpret_cast<const bf16x8*>(krp + j * D_DIM);
        vR[j].v8 = *reinterpret_cast<const bf16x8*>(vrp + j * D_DIM);
      }
      krp += (size_t)KVB * D_DIM;
      vrp += (size_t)KVB * D_DIM;
    }

    // ---- QK^T: S^T[kv][q] ----
    floatx16 st[2];
#pragma unroll
    for (int kvh = 0; kvh < 2; ++kvh)
#pragma unroll
      for (int r = 0; r < 16; ++r) st[kvh][r] = 0.f;
    __builtin_amdgcn_s_setprio(1);
#pragma unroll
    for (int kc = 0; kc < 8; ++kc) {
      bf16x8 kf0 = *reinterpret_cast<const bf16x8*>(
          smem + cb + Rk[kc & 3] + (unsigned)(kc * 2048));
      bf16x8 kf1 = *reinterpret_cast<const bf16x8*>(
          smem + cb + Rk[kc & 3] + (unsigned)(kc * 2048 + 512));
      st[0] = __builtin_amdgcn_mfma_f32_32x32x16_bf16(kf0, qf[kc], st[0], 0, 0, 0);
      st[1] = __builtin_amdgcn_mfma_f32_32x32x16_bf16(kf1, qf[kc], st[1], 0, 0, 0);
    }
    __builtin_amdgcn_s_setprio(0);

    // ---- write staged tile t+1 into buf[nxt] EARLY (drains under
    //      softmax VALU + PV; legal: top barrier proved no readers) ----
    if (hn) {
      const unsigned nb = cb ^ 16384u;
#pragma unroll
      for (int j = 0; j < 4; ++j)
        *reinterpret_cast<bf16x8*>(smem + nb + Wk_[j]) = kR[j];
#pragma unroll
      for (int e = 0; e < 8; ++e) {
        uint2 w;
        w.x = (unsigned)vR[0].s[e] | ((unsigned)vR[1].s[e] << 16);
        w.y = (unsigned)vR[2].s[e] | ((unsigned)vR[3].s[e] << 16);
        *reinterpret_cast<uint2*>(smem + nb + Wv_[e]) = w;
      }
    }

    // ---- softmax (exp2 domain), tree max/sum, T13 defer-rescale ----
    float t8[8];
#pragma unroll
    for (int i = 0; i < 8; ++i)
      t8[i] = fmaxf(fmaxf(st[0][i], st[0][i + 8]), fmaxf(st[1][i], st[1][i + 8]));
    float pmax = fmaxf(fmaxf(fmaxf(t8[0], t8[4]), fmaxf(t8[1], t8[5])),
                       fmaxf(fmaxf(t8[2], t8[6]), fmaxf(t8[3], t8[7])));
    pmax = fmaxf(pmax, __shfl_xor(pmax, 32));
    if (!__all(pmax - m_r <= 8.0f)) {
      float mnew = fmaxf(m_r, pmax);
      float sc_f = __builtin_amdgcn_exp2f(m_r - mnew);
      m_r = mnew;
      l_r *= sc_f;
#pragma unroll
      for (int d = 0; d < 4; ++d)
#pragma unroll
        for (int r = 0; r < 16; ++r) ot[d][r] *= sc_f;
    }
#pragma unroll
    for (int kvh = 0; kvh < 2; ++kvh)
#pragma unroll
      for (int r = 0; r < 16; ++r)
        st[kvh][r] = __builtin_amdgcn_exp2f(st[kvh][r] - m_r);
    float s8[8];
#pragma unroll
    for (int i = 0; i < 8; ++i)
      s8[i] = (st[0][i] + st[0][i + 8]) + (st[1][i] + st[1][i + 8]);
    float psum = ((s8[0] + s8[4]) + (s8[1] + s8[5])) +
                 ((s8[2] + s8[6]) + (s8[3] + s8[7]));
    psum += __shfl_xor(psum, 32);
    l_r += psum;

    // ---- P^T B-fragments + PV ----
#pragma unroll
    for (int ks = 0; ks < 4; ++ks) {
      const int kvh = ks >> 1;
      const int r2a = (2 * ks) & 3;
      const int r2b = r2a + 1;
      unsigned ua0 = pack2(st[kvh][r2a * 4 + 0], st[kvh][r2a * 4 + 1]);
      unsigned ua1 = pack2(st[kvh][r2a * 4 + 2], st[kvh][r2a * 4 + 3]);
      unsigned ub0 = pack2(st[kvh][r2b * 4 + 0], st[kvh][r2b * 4 + 1]);
      unsigned ub1 = pack2(st[kvh][r2b * 4 + 2], st[kvh][r2b * 4 + 3]);
      union { unsigned u[4]; bf16x8 v8; } pw;
#if __has_builtin(__builtin_amdgcn_permlane32_swap)
      {
        auto r0 = __builtin_amdgcn_permlane32_swap(ua0, ub0, false, false);
        auto r1 = __builtin_amdgcn_permlane32_swap(ua1, ub1, false, false);
        pw.u[0] = r0[0];  // kv offsets 0-1 of group 2ks+h
        pw.u[1] = r1[0];  // offsets 2-3
        pw.u[2] = r0[1];  // offsets 4-5
        pw.u[3] = r1[1];  // offsets 6-7
      }
#else
      {
        unsigned a0x = __shfl_xor(ua0, 32), a1x = __shfl_xor(ua1, 32);
        unsigned b0x = __shfl_xor(ub0, 32), b1x = __shfl_xor(ub1, 32);
        pw.u[0] = h ? b0x : ua0;
        pw.u[1] = h ? b1x : ua1;
        pw.u[2] = h ? ub0 : a0x;
        pw.u[3] = h ? ub1 : a1x;
      }
#endif
      __builtin_amdgcn_s_setprio(1);
#pragma unroll
      for (int db = 0; db < 4; ++db) {
        const unsigned base = (db & 1) ? Rv1 : Rv0;
        bf16x8 vf = *reinterpret_cast<const bf16x8*>(
            smem + cb + base + (unsigned)(ks * 4096 + db * 512));
        ot[db] = __builtin_amdgcn_mfma_f32_32x32x16_bf16(vf, pw.v8, ot[db], 0, 0, 0);
      }
      __builtin_amdgcn_s_setprio(0);
    }
  }

  // ==== fused epilogue: O -> LDS; Wo -> LDS; proj; write fp32 d_out ====
  __syncthreads();  // all waves done with K/V LDS

  // (a) O^T -> LDS[0..32K) as row-major bf16 (divided by l), swizzled
  {
    const float inv_l = 1.0f / l_r;
    const int qloc = wave * 32 + ql;
#pragma unroll
    for (int db = 0; db < 4; ++db)
#pragma unroll
      for (int r = 0; r < 16; ++r) {
        int d = db * 32 + (r & 3) + 8 * (r >> 2) + 4 * h;
        *reinterpret_cast<__bf16*>(smem + swz(qloc, qloc * 256u + d * 2u)) =
            (__bf16)(ot[db][r] * inv_l);
      }
  }
  // (b) Wo fp32 -> LDS[32K..64K) as bf16, swizzled rows
  for (int it = 0; it < 16; ++it) {
    int lin = it * 1024 + tid * 4;
    float4 w4 = *reinterpret_cast<const float4*>(Wo + lin);
    int r = lin >> 7, c = lin & 127;
    unsigned off = 32768u + swz(r, (unsigned)(r * 256 + c * 2));
    __bf16 b4[4] = {(__bf16)w4.x, (__bf16)w4.y, (__bf16)w4.z, (__bf16)w4.w};
    *reinterpret_cast<uint2*>(smem + off) = *reinterpret_cast<uint2*>(b4);
  }
  __syncthreads();

  // (c) proj: out[q][e] = O[q][:] . Wo[e][:] + bo[e]
  const int g4 = lane >> 4;      // 0..3 (k-slice group)
  const int lr = lane & 15;      // A row / C col
  float be[8];
#pragma unroll
  for (int nt = 0; nt < 8; ++nt) be[nt] = bo[nt * 16 + lr];

#pragma unroll
  for (int rt = 0; rt < 2; ++rt) {
    const int arow = wave * 32 + rt * 16 + lr;  // local O row
    floatx4 acc[8];
#pragma unroll
    for (int i = 0; i < 8; ++i) acc[i] = floatx4{0.f, 0.f, 0.f, 0.f};
#pragma unroll
    for (int kc = 0; kc < 4; ++kc) {
      bf16x8 af = *reinterpret_cast<const bf16x8*>(
          smem + swz(arow, (unsigned)(arow * 256 + (kc * 32 + g4 * 8) * 2)));
#pragma unroll
      for (int nt = 0; nt < 8; ++nt) {
        int wrow = nt * 16 + lr;
        bf16x8 wf = *reinterpret_cast<const bf16x8*>(
            smem + 32768u + swz(wrow, (unsigned)(wrow * 256 + (kc * 32 + g4 * 8) * 2)));
        acc[nt] = __builtin_amdgcn_mfma_f32_16x16x32_bf16(af, wf, acc[nt], 0, 0, 0);
      }
    }
#pragma unroll
    for (int nt = 0; nt < 8; ++nt) {
      int e = nt * 16 + lr;
#pragma unroll
      for (int j = 0; j < 4; ++j) {
        int row = qbase + wave * 32 + rt * 16 + g4 * 4 + j;
        out[((size_t)bh * S_LEN + row) * D_DIM + e] = acc[nt][j] + be[nt];
      }
    }
  }
}

// ---------------------------------------------------------------------------
// attn_kernel (fallback path, r13-proven; only used if ws_size too small)
// ---------------------------------------------------------------------------
__global__ __launch_bounds__(256, 2) void attn_kernel(
    const __bf16* __restrict__ q, const __bf16* __restrict__ k,
    const __bf16* __restrict__ v, __bf16* __restrict__ o) {
  __shared__ alignas(16) unsigned char smem[65536];

  const int tid = threadIdx.x;
  const int wave = tid >> 6, lane = tid & 63;
  const int ql = lane & 31;
  const int h = lane >> 5;

  const int bh = blockIdx.x;
  const int qbase = blockIdx.y * 128;
  const __bf16* qp = q + (size_t)bh * S_LEN * D_DIM;
  const __bf16* kp = k + (size_t)bh * S_LEN * D_DIM;
  const __bf16* vp = v + (size_t)bh * S_LEN * D_DIM;
  __bf16* op = o + (size_t)bh * S_LEN * D_DIM;

  const int qrow = qbase + wave * 32 + ql;
  bf16x8 qf[8];
#pragma unroll
  for (int kc = 0; kc < 8; ++kc)
    qf[kc] = *reinterpret_cast<const bf16x8*>(
        qp + (size_t)qrow * D_DIM + kc * 16 + h * 8);

  floatx16 ot[4];
#pragma unroll
  for (int d = 0; d < 4; ++d)
#pragma unroll
    for (int r = 0; r < 16; ++r) ot[d][r] = 0.f;
  float m_r = -1e30f, l_r = 0.f;

  const int cc = tid & 15;
  const int pr4 = (tid >> 4) * 4;
  const int ce = cc * 8;

  unsigned Rk[4];
#pragma unroll
  for (int x = 0; x < 4; ++x)
    Rk[x] = (unsigned)(h * 1024) +
            (((unsigned)(ql * 16)) ^ ((unsigned)h << 4) ^ ((unsigned)x << 5));
  const unsigned Rv0 = 32768u + (unsigned)(h * 2048) +
                       (((unsigned)(ql * 16)) ^ (((unsigned)(ql >> 3)) << 4));
  const unsigned Rv1 = Rv0 ^ 64u;
  const unsigned kx = ((unsigned)(cc & 7)) << 4;
  unsigned Wk_[4];
#pragma unroll
  for (int j = 0; j < 4; ++j)
    Wk_[j] = ((unsigned)(cc * 1024 + (pr4 + j) * 16)) ^ kx;
  unsigned Wv_[8];
  {
    unsigned vbase = 32768u + (unsigned)((pr4 >> 3) * 2048 + ce * 16 + (pr4 & 7) * 2);
#pragma unroll
    for (int e = 0; e < 8; ++e)
      Wv_[e] = vbase | (((unsigned)e << 4) ^ kx);
  }

  {
    const __bf16* kr = kp + (size_t)pr4 * D_DIM + ce;
    const __bf16* vr = vp + (size_t)pr4 * D_DIM + ce;
    bf16x8 kR[4];
    union { bf16x8 v8; unsigned short s[8]; } vR[4];
#pragma unroll
    for (int j = 0; j < 4; ++j) {
      kR[j] = *reinterpret_cast<const bf16x8*>(kr + j * D_DIM);
      vR[j].v8 = *reinterpret_cast<const bf16x8*>(vr + j * D_DIM);
    }
#pragma unroll
    for (int j = 0; j < 4; ++j)
      *reinterpret_cast<bf16x8*>(smem + Wk_[j]) = kR[j];
#pragma unroll
    for (int e = 0; e < 8; ++e) {
      uint2 w;
      w.x = (unsigned)vR[0].s[e] | ((unsigned)vR[1].s[e] << 16);
      w.y = (unsigned)vR[2].s[e] | ((unsigned)vR[3].s[e] << 16);
      *reinterpret_cast<uint2*>(smem + Wv_[e]) = w;
    }
  }

  const __bf16* krp = kp + ((size_t)KVB + pr4) * D_DIM + ce;
  const __bf16* vrp = vp + ((size_t)KVB + pr4) * D_DIM + ce;

#pragma unroll 2
  for (int t = 0; t < NKV; ++t) {
    const unsigned cb = (unsigned)(t & 1) * 16384u;
    const bool hn = (t + 1 < NKV);

    __syncthreads();

    bf16x8 kR[4];
    union { bf16x8 v8; unsigned short s[8]; } vR[4];
    if (hn) {
#pragma unroll
      for (int j = 0; j < 4; ++j) {
        kR[j] = *reinterpret_cast<const bf16x8*>(krp + j * D_DIM);
        vR[j].v8 = *reinterpret_cast<const bf16x8*>(vrp + j * D_DIM);
      }
      krp += (size_t)KVB * D_DIM;
      vrp += (size_t)KVB * D_DIM;
    }

    floatx16 st[2];
#pragma unroll
    for (int kvh = 0; kvh < 2; ++kvh)
#pragma unroll
      for (int r = 0; r < 16; ++r) st[kvh][r] = 0.f;
    __builtin_amdgcn_s_setprio(1);
#pragma unroll
    for (int kc = 0; kc < 8; ++kc) {
      bf16x8 kf0 = *reinterpret_cast<const bf16x8*>(
          smem + cb + Rk[kc & 3] + (unsigned)(kc * 2048));
      bf16x8 kf1 = *reinterpret_cast<const bf16x8*>(
          smem + cb + Rk[kc & 3] + (unsigned)(kc * 2048 + 512));
      st[0] = __builtin_amdgcn_mfma_f32_32x32x16_bf16(kf0, qf[kc], st[0], 0, 0, 0);
      st[1] = __builtin_amdgcn_mfma_f32_32x32x16_bf16(kf1, qf[kc], st[1], 0, 0, 0);
    }
    __builtin_amdgcn_s_setprio(0);

    if (hn) {
      const unsigned nb = cb ^ 16384u;
#pragma unroll
      for (int j = 0; j < 4; ++j)
        *reinterpret_cast<bf16x8*>(smem + nb + Wk_[j]) = kR[j];
#pragma unroll
      for (int e = 0; e < 8; ++e) {
        uint2 w;
        w.x = (unsigned)vR[0].s[e] | ((unsigned)vR[1].s[e] << 16);
        w.y = (unsigned)vR[2].s[e] | ((unsigned)vR[3].s[e] << 16);
        *reinterpret_cast<uint2*>(smem + nb + Wv_[e]) = w;
      }
    }

    float t8[8];
#pragma unroll
    for (int i = 0; i < 8; ++i)
      t8[i] = fmaxf(fmaxf(st[0][i], st[0][i + 8]), fmaxf(st[1][i], st[1][i + 8]));
    float pmax = fmaxf(fmaxf(fmaxf(t8[0], t8[4]), fmaxf(t8[1], t8[5])),
                       fmaxf(fmaxf(t8[2], t8[6]), fmaxf(t8[3], t8[7])));
    pmax = fmaxf(pmax, __shfl_xor(pmax, 32));
    if (!__all(pmax - m_r <= 8.0f)) {
      float mnew = fmaxf(m_r, pmax);
      float sc_f = __builtin_amdgcn_exp2f(m_r - mnew);
      m_r = mnew;
      l_r *= sc_f;
#pragma unroll
      for (int d = 0; d < 4; ++d)
#pragma unroll
        for (int r = 0; r < 16; ++r) ot[d][r] *= sc_f;
    }
#pragma unroll
    for (int kvh = 0; kvh < 2; ++kvh)
#pragma unroll
      for (int r = 0; r < 16; ++r)
        st[kvh][r] = __builtin_amdgcn_exp2f(st[kvh][r] - m_r);
    float s8[8];
#pragma unroll
    for (int i = 0; i < 8; ++i)
      s8[i] = (st[0][i] + st[0][i + 8]) + (st[1][i] + st[1][i + 8]);
    float psum = ((s8[0] + s8[4]) + (s8[1] + s8[5])) +
                 ((s8[2] + s8[6]) + (s8[3] + s8[7]));
    psum += __shfl_xor(psum, 32);
    l_r += psum;

#pragma unroll
    for (int ks = 0; ks < 4; ++ks) {
      const int kvh = ks >> 1;
      const int r2a = (2 * ks) & 3;
      const int r2b = r2a + 1;
      unsigned ua0 = pack2(st[kvh][r2a * 4 + 0], st[kvh][r2a * 4 + 1]);
      unsigned ua1 = pack2(st[kvh][r2a * 4 + 2], st[kvh][r2a * 4 + 3]);
      unsigned ub0 = pack2(st[kvh][r2b * 4 + 0], st[kvh][r2b * 4 + 1]);
      unsigned ub1 = pack2(st[kvh][r2b * 4 + 2], st[kvh][r2b * 4 + 3]);
      union { unsigned u[4]; bf16x8 v8; } pw;
#if __has_builtin(__builtin_amdgcn_permlane32_swap)
      {
        auto r0 = __builtin_amdgcn_permlane32_swap(ua0, ub0, false, false);
        auto r1 = __builtin_amdgcn_permlane32_swap(ua1, ub1, false, false);
        pw.u[0] = r0[0];
        pw.u[1] = r1[0];
        pw.u[2] = r0[1];
        pw.u[3] = r1[1];
      }
#else
      {
        unsigned a0x = __shfl_xor(ua0, 32), a1x = __shfl_xor(ua1, 32);
        unsigned b0x = __shfl_xor(ub0, 32), b1x = __shfl_xor(ub1, 32);
        pw.u[0] = h ? b0x : ua0;
        pw.u[1] = h ? b1x : ua1;
        pw.u[2] = h ? ub0 : a0x;
        pw.u[3] = h ? ub1 : a1x;
      }
#endif
      __builtin_amdgcn_s_setprio(1);
#pragma unroll
      for (int db = 0; db < 4; ++db) {
        const unsigned base = (db & 1) ? Rv1 : Rv0;
        bf16x8 vf = *reinterpret_cast<const bf16x8*>(
            smem + cb + base + (unsigned)(ks * 4096 + db * 512));
        ot[db] = __builtin_amdgcn_mfma_f32_32x32x16_bf16(vf, pw.v8, ot[db], 0, 0, 0);
      }
      __builtin_amdgcn_s_setprio(0);
    }
  }

  __syncthreads();
  const float inv_l = 1.0f / l_r;
  const int qloc = wave * 32 + ql;
#pragma unroll
  for (int db = 0; db < 4; ++db)
#pragma unroll
    for (int r = 0; r < 16; ++r) {
      int d = db * 32 + (r & 3) + 8 * (r >> 2) + 4 * h;
      *reinterpret_cast<__bf16*>(smem + swz(qloc, qloc * 256u + d * 2u)) =
          (__bf16)(ot[db][r] * inv_l);
    }
  __syncthreads();
#pragma unroll
  for (int it = 0; it < 8; ++it) {
    int r = tid >> 1;
    int c = (tid & 1) * 64 + it * 8;
    bf16x8 val = *reinterpret_cast<const bf16x8*>(smem + swz(r, r * 256u + c * 2u));
    *reinterpret_cast<bf16x8*>(op + (size_t)(qbase + r) * D_DIM + c) = val;
  }
}

// ---------------------------------------------------------------------------
extern "C" void kernel_launch(void* const* d_in, const int* in_sizes, int n_in,
                              void* d_out, int out_size, void* d_ws, size_t ws_size,
                              hipStream_t stream) {
  const float* query = (const float*)d_in[0];
  const float* key_  = (const float*)d_in[1];
  const float* value = (const float*)d_in[2];
  const float* Wq = (const float*)d_in[3];
  const float* bq = (const float*)d_in[4];
  const float* Wk = (const float*)d_in[5];
  const float* bk = (const float*)d_in[6];
  const float* Wv = (const float*)d_in[7];
  const float* bv = (const float*)d_in[8];
  const float* Wo = (const float*)d_in[9];
  const float* bo = (const float*)d_in[10];

  const size_t nelem = (size_t)NTOK * D_DIM;
  const float qscale = 0.1275174490036f;  // log2(e)/sqrt(128)
  dim3 blk(256);

  if (ws_size >= 3 * nelem * sizeof(__bf16)) {
    // fused path: q,k,v all in d_ws; d_out written by the fused epilogue.
    __bf16* vws = (__bf16*)d_ws;
    __bf16* qws = vws + nelem;
    __bf16* kws = qws + nelem;

    qkv_proj_kernel<<<dim3(NTOK / 256, 3), blk, 0, stream>>>(
        query, key_, value, Wq, Wk, Wv, bq, bk, bv, qws, kws, vws, qscale);

    attn_fused_kernel<<<dim3(32, 16), blk, 0, stream>>>(
        qws, kws, vws, Wo, bo, (float*)d_out);
  } else {
    // fallback (r13 path): q/k scratch inside d_out, aws in d_ws
    __bf16* vws = (__bf16*)d_ws;
    __bf16* aws = vws + nelem;
    __bf16* qws = (__bf16*)d_out;
    __bf16* kws = qws + nelem;

    qkv_proj_kernel<<<dim3(NTOK / 256, 3), blk, 0, stream>>>(
        query, key_, value, Wq, Wk, Wv, bq, bk, bv, qws, kws, vws, qscale);

    attn_kernel<<<dim3(32, 16), blk, 0, stream>>>(qws, kws, vws, aws);

    o_proj_kernel<<<NTOK / 256, blk, 0, stream>>>(aws, Wo, bo, (float*)d_out);
  }
}